// Round 2
// baseline (2614.432 us; speedup 1.0000x reference)
//
#include <hip/hip_runtime.h>
#include <math.h>

#define N_NODES 50000
#define E_EDGES 800000
#define E_GT    200000

// ---------- K1: h0 = [x | zeros(8)] ----------
__global__ void k_init_h0(const float* __restrict__ x, float* __restrict__ h0) {
    int i = blockIdx.x * blockDim.x + threadIdx.x;
    if (i >= N_NODES * 24) return;
    int n = i / 24, c = i % 24;
    h0[i] = (c < 16) ? x[n * 16 + c] : 0.0f;
}

// ---------- K2: edge-feature embedding scatter + degree ----------
__global__ void k_edge_embed(const int* __restrict__ ei, const int* __restrict__ ef,
                             const float* __restrict__ embT, const float* __restrict__ embA,
                             float* __restrict__ h0, float* __restrict__ deg) {
    int e = blockIdx.x * blockDim.x + threadIdx.x;
    if (e >= E_EDGES) return;
    int s = ei[e], d = ei[E_EDGES + e];
    int tr = ef[2 * e], ac = ef[2 * e + 1];
#pragma unroll
    for (int j = 0; j < 4; ++j) {
        atomicAdd(&h0[s * 24 + 16 + j], embT[tr * 4 + j]);  // agg_trigger by src
        atomicAdd(&h0[d * 24 + 20 + j], embA[ac * 4 + j]);  // agg_action by dst
    }
    atomicAdd(&deg[d], 1.0f);
}

// ---------- K3: agg1[dst] += h0[src] (24-wide) ----------
__global__ void k_agg24(const int* __restrict__ ei, const float* __restrict__ h0,
                        float* __restrict__ agg1) {
    int i = blockIdx.x * blockDim.x + threadIdx.x;
    if (i >= E_EDGES * 24) return;
    int e = i / 24, c = i % 24;
    int s = ei[e], d = ei[E_EDGES + e];
    atomicAdd(&agg1[d * 24 + c], h0[s * 24 + c]);
}

// ---------- K4: h1 = relu(mean_agg1 @ W1l + h0 @ W1r + b1), 8 nodes/block ----------
__global__ __launch_bounds__(256) void k_sage1(
        const float* __restrict__ agg1, const float* __restrict__ h0,
        const float* __restrict__ deg,
        const float* __restrict__ W1l, const float* __restrict__ W1r,
        const float* __restrict__ b1, float* __restrict__ h1) {
    __shared__ float s_agg[8][24], s_h[8][24], s_inv[8];
    int nb = blockIdx.x * 8;
    int t = threadIdx.x;
    if (t < 8) { float d = deg[nb + t]; s_inv[t] = 1.0f / fmaxf(d, 1.0f); }
    if (t < 192) {
        int g = t / 24, c = t % 24;
        s_agg[g][c] = agg1[(nb + g) * 24 + c];
        s_h[g][c]   = h0[(nb + g) * 24 + c];
    }
    __syncthreads();
    float accA[8] = {0,0,0,0,0,0,0,0}, accH[8] = {0,0,0,0,0,0,0,0};
    for (int k = 0; k < 24; ++k) {
        float wl = W1l[k * 256 + t], wr = W1r[k * 256 + t];
#pragma unroll
        for (int g = 0; g < 8; ++g) {
            accA[g] += s_agg[g][k] * wl;
            accH[g] += s_h[g][k] * wr;
        }
    }
    float b = b1[t];
#pragma unroll
    for (int g = 0; g < 8; ++g) {
        float v = b + s_inv[g] * accA[g] + accH[g];
        h1[(nb + g) * 256 + t] = fmaxf(v, 0.0f);
    }
}

// ---------- K5: agg2[dst] += h1[src] (256-wide), one edge per block ----------
__global__ __launch_bounds__(256) void k_agg256(
        const int* __restrict__ ei, const float* __restrict__ h1,
        float* __restrict__ agg2) {
    int e = blockIdx.x;
    int c = threadIdx.x;
    int s = ei[e], d = ei[E_EDGES + e];
    atomicAdd(&agg2[d * 256 + c], h1[s * 256 + c]);
}

// ---------- K6: h2 = relu(mean_agg2 @ W2l + h1 @ W2r + b2), 8 nodes/block ----------
__global__ __launch_bounds__(128) void k_sage2(
        const float* __restrict__ agg2, const float* __restrict__ h1,
        const float* __restrict__ deg,
        const float* __restrict__ W2l, const float* __restrict__ W2r,
        const float* __restrict__ b2, float* __restrict__ h2) {
    __shared__ float s_agg[8][256], s_h[8][256], s_inv[8];
    int nb = blockIdx.x * 8;
    int t = threadIdx.x;
    if (t < 8) { float d = deg[nb + t]; s_inv[t] = 1.0f / fmaxf(d, 1.0f); }
    for (int i = t; i < 8 * 256; i += 128) {
        int g = i >> 8, c = i & 255;
        s_agg[g][c] = agg2[(nb + g) * 256 + c];
        s_h[g][c]   = h1[(nb + g) * 256 + c];
    }
    __syncthreads();
    float accA[8] = {0,0,0,0,0,0,0,0}, accH[8] = {0,0,0,0,0,0,0,0};
    for (int k = 0; k < 256; ++k) {
        float wl = W2l[k * 128 + t], wr = W2r[k * 128 + t];
#pragma unroll
        for (int g = 0; g < 8; ++g) {
            accA[g] += s_agg[g][k] * wl;
            accH[g] += s_h[g][k] * wr;
        }
    }
    float b = b2[t];
#pragma unroll
    for (int g = 0; g < 8; ++g) {
        float v = b + s_inv[g] * accA[g] + accH[g];
        h2[(nb + g) * 128 + t] = fmaxf(v, 0.0f);
    }
}

// ---------- K7: classifier, 16 GT-edges per block ----------
__global__ __launch_bounds__(128) void k_classifier(
        const int* __restrict__ eg, const float* __restrict__ h2,
        const float* __restrict__ Wc1, const float* __restrict__ bc1,
        const float* __restrict__ Wc2, const float* __restrict__ bc2,
        float* __restrict__ out) {
    __shared__ float s_feat[16][256];
    __shared__ float s_hid[16][128];
    int eb = blockIdx.x * 16;
    int t = threadIdx.x;  // 128
#pragma unroll
    for (int g = 0; g < 16; ++g) {
        int s = eg[eb + g], d = eg[E_GT + eb + g];
        s_feat[g][t]       = h2[s * 128 + t];
        s_feat[g][128 + t] = h2[d * 128 + t];
    }
    __syncthreads();
    float acc[16];
#pragma unroll
    for (int g = 0; g < 16; ++g) acc[g] = bc1[t];
    for (int k = 0; k < 256; ++k) {
        float w = Wc1[k * 128 + t];
#pragma unroll
        for (int g = 0; g < 16; ++g) acc[g] += s_feat[g][k] * w;
    }
#pragma unroll
    for (int g = 0; g < 16; ++g) s_hid[g][t] = fmaxf(acc[g], 0.0f);
    __syncthreads();
    for (int o = t; o < 552; o += 128) {
        float a2[16];
#pragma unroll
        for (int g = 0; g < 16; ++g) a2[g] = bc2[o];
        for (int k = 0; k < 128; ++k) {
            float w = Wc2[k * 552 + o];
#pragma unroll
            for (int g = 0; g < 16; ++g) a2[g] += s_hid[g][k] * w;
        }
#pragma unroll
        for (int g = 0; g < 16; ++g) {
            out[(eb + g) * 552 + o] = 1.0f / (1.0f + expf(-a2[g]));
        }
    }
}

extern "C" void kernel_launch(void* const* d_in, const int* in_sizes, int n_in,
                              void* d_out, int out_size, void* d_ws, size_t ws_size,
                              hipStream_t stream) {
    const float* x    = (const float*)d_in[0];
    const int*   ei   = (const int*)d_in[1];
    const int*   eg   = (const int*)d_in[2];
    const int*   ef   = (const int*)d_in[3];
    const float* embT = (const float*)d_in[4];
    const float* embA = (const float*)d_in[5];
    const float* W1l  = (const float*)d_in[6];
    const float* W1r  = (const float*)d_in[7];
    const float* b1   = (const float*)d_in[8];
    const float* W2l  = (const float*)d_in[9];
    const float* W2r  = (const float*)d_in[10];
    const float* b2   = (const float*)d_in[11];
    const float* Wc1  = (const float*)d_in[12];
    const float* bc1  = (const float*)d_in[13];
    const float* Wc2  = (const float*)d_in[14];
    const float* bc2  = (const float*)d_in[15];
    float* out = (float*)d_out;

    float* h0   = (float*)d_ws;            // N*24
    float* deg  = h0   + N_NODES * 24;     // N
    float* agg1 = deg  + N_NODES;          // N*24
    float* agg2 = agg1 + N_NODES * 24;     // N*256
    float* h1   = agg2 + N_NODES * 256;    // N*256
    float* h2   = h1   + N_NODES * 256;    // N*128

    // zero deg + agg1 + agg2 in one memset (contiguous)
    hipMemsetAsync(deg, 0, (size_t)N_NODES * (1 + 24 + 256) * sizeof(float), stream);

    k_init_h0<<<(N_NODES * 24 + 255) / 256, 256, 0, stream>>>(x, h0);
    k_edge_embed<<<(E_EDGES + 255) / 256, 256, 0, stream>>>(ei, ef, embT, embA, h0, deg);
    k_agg24<<<(E_EDGES * 24 + 255) / 256, 256, 0, stream>>>(ei, h0, agg1);
    k_sage1<<<N_NODES / 8, 256, 0, stream>>>(agg1, h0, deg, W1l, W1r, b1, h1);
    k_agg256<<<E_EDGES, 256, 0, stream>>>(ei, h1, agg2);
    k_sage2<<<N_NODES / 8, 128, 0, stream>>>(agg2, h1, deg, W2l, W2r, b2, h2);
    k_classifier<<<E_GT / 16, 128, 0, stream>>>(eg, h2, Wc1, bc1, Wc2, bc2, out);
}

// Round 4
// 2038.278 us; speedup vs baseline: 1.2827x; 1.2827x over previous
//
#include <hip/hip_runtime.h>
#include <hip/hip_bf16.h>
#include <math.h>

#define N_NODES 50000
#define E_EDGES 800000
#define E_GT    200000

typedef __attribute__((ext_vector_type(8))) short short8;
typedef __attribute__((ext_vector_type(4))) float f32x4;

// ---------- K1: h0 = [x | zeros(8)] ----------
__global__ void k_init_h0(const float* __restrict__ x, float* __restrict__ h0) {
    int i = blockIdx.x * blockDim.x + threadIdx.x;
    if (i >= N_NODES * 24) return;
    int n = i / 24, c = i % 24;
    h0[i] = (c < 16) ? x[n * 16 + c] : 0.0f;
}

// ---------- K2: edge-feature embedding scatter + degree ----------
__global__ void k_edge_embed(const int* __restrict__ ei, const int* __restrict__ ef,
                             const float* __restrict__ embT, const float* __restrict__ embA,
                             float* __restrict__ h0, float* __restrict__ deg) {
    int e = blockIdx.x * blockDim.x + threadIdx.x;
    if (e >= E_EDGES) return;
    int s = ei[e], d = ei[E_EDGES + e];
    int tr = ef[2 * e], ac = ef[2 * e + 1];
#pragma unroll
    for (int j = 0; j < 4; ++j) {
        atomicAdd(&h0[s * 24 + 16 + j], embT[tr * 4 + j]);  // agg_trigger by src
        atomicAdd(&h0[d * 24 + 20 + j], embA[ac * 4 + j]);  // agg_action by dst
    }
    atomicAdd(&deg[d], 1.0f);
}

// ---------- K3: agg1[dst] += h0[src] (24-wide) ----------
__global__ void k_agg24(const int* __restrict__ ei, const float* __restrict__ h0,
                        float* __restrict__ agg1) {
    int i = blockIdx.x * blockDim.x + threadIdx.x;
    if (i >= E_EDGES * 24) return;
    int e = i / 24, c = i % 24;
    int s = ei[e], d = ei[E_EDGES + e];
    atomicAdd(&agg1[d * 24 + c], h0[s * 24 + c]);
}

// ---------- K4: h1 = relu(mean_agg1 @ W1l + h0 @ W1r + b1), 8 nodes/block ----------
__global__ __launch_bounds__(256) void k_sage1(
        const float* __restrict__ agg1, const float* __restrict__ h0,
        const float* __restrict__ deg,
        const float* __restrict__ W1l, const float* __restrict__ W1r,
        const float* __restrict__ b1, float* __restrict__ h1) {
    __shared__ float s_agg[8][24], s_h[8][24], s_inv[8];
    int nb = blockIdx.x * 8;
    int t = threadIdx.x;
    if (t < 8) { float d = deg[nb + t]; s_inv[t] = 1.0f / fmaxf(d, 1.0f); }
    if (t < 192) {
        int g = t / 24, c = t % 24;
        s_agg[g][c] = agg1[(nb + g) * 24 + c];
        s_h[g][c]   = h0[(nb + g) * 24 + c];
    }
    __syncthreads();
    float accA[8] = {0,0,0,0,0,0,0,0}, accH[8] = {0,0,0,0,0,0,0,0};
    for (int k = 0; k < 24; ++k) {
        float wl = W1l[k * 256 + t], wr = W1r[k * 256 + t];
#pragma unroll
        for (int g = 0; g < 8; ++g) {
            accA[g] += s_agg[g][k] * wl;
            accH[g] += s_h[g][k] * wr;
        }
    }
    float b = b1[t];
#pragma unroll
    for (int g = 0; g < 8; ++g) {
        float v = b + s_inv[g] * accA[g] + accH[g];
        h1[(nb + g) * 256 + t] = fmaxf(v, 0.0f);
    }
}

// ---------- K5: agg2[dst] += h1[src] (256-wide), one edge per block ----------
__global__ __launch_bounds__(256) void k_agg256(
        const int* __restrict__ ei, const float* __restrict__ h1,
        float* __restrict__ agg2) {
    int e = blockIdx.x;
    int c = threadIdx.x;
    int s = ei[e], d = ei[E_EDGES + e];
    atomicAdd(&agg2[d * 256 + c], h1[s * 256 + c]);
}

// ---------- K6: h2 = relu(mean_agg2 @ W2l + h1 @ W2r + b2) -> bf16 ----------
__global__ __launch_bounds__(128) void k_sage2(
        const float* __restrict__ agg2, const float* __restrict__ h1,
        const float* __restrict__ deg,
        const float* __restrict__ W2l, const float* __restrict__ W2r,
        const float* __restrict__ b2, __hip_bfloat16* __restrict__ h2b) {
    __shared__ float s_agg[8][256], s_h[8][256], s_inv[8];
    int nb = blockIdx.x * 8;
    int t = threadIdx.x;
    if (t < 8) { float d = deg[nb + t]; s_inv[t] = 1.0f / fmaxf(d, 1.0f); }
    for (int i = t; i < 8 * 256; i += 128) {
        int g = i >> 8, c = i & 255;
        s_agg[g][c] = agg2[(nb + g) * 256 + c];
        s_h[g][c]   = h1[(nb + g) * 256 + c];
    }
    __syncthreads();
    float accA[8] = {0,0,0,0,0,0,0,0}, accH[8] = {0,0,0,0,0,0,0,0};
    for (int k = 0; k < 256; ++k) {
        float wl = W2l[k * 128 + t], wr = W2r[k * 128 + t];
#pragma unroll
        for (int g = 0; g < 8; ++g) {
            accA[g] += s_agg[g][k] * wl;
            accH[g] += s_h[g][k] * wr;
        }
    }
    float b = b2[t];
#pragma unroll
    for (int g = 0; g < 8; ++g) {
        float v = b + s_inv[g] * accA[g] + accH[g];
        h2b[(nb + g) * 128 + t] = __float2bfloat16(fmaxf(v, 0.0f));
    }
}

// ---------- K-prep: transpose weights to bf16, k-contiguous rows ----------
// w1t[n][k] (128x256), w2t[n][k] (560x128, rows 552..559 zero-padded)
__global__ void k_prep_w(const float* __restrict__ Wc1, const float* __restrict__ Wc2,
                         __hip_bfloat16* __restrict__ w1t, __hip_bfloat16* __restrict__ w2t) {
    int i = blockIdx.x * blockDim.x + threadIdx.x;
    if (i < 128 * 256) {
        int n = i >> 8, k = i & 255;
        w1t[i] = __float2bfloat16(Wc1[k * 128 + n]);
    }
    if (i < 560 * 128) {
        int n = i >> 7, k = i & 127;
        w2t[i] = __float2bfloat16(n < 552 ? Wc2[k * 552 + n] : 0.0f);
    }
}

// ---------- K7: classifier via bf16 MFMA ----------
// Per wave: 16 edges. GEMM1 (K=256 -> 128) then GEMM2 (K=128 -> 552) + sigmoid.
// A-frags k-contiguous (verified m97 gemm_bt pattern); B from pre-transposed
// weights; hidden layer through per-wave XOR-swizzled LDS (G4: byte ^= (row&7)<<4).
__global__ __launch_bounds__(256) void k_classifier_mfma(
        const int* __restrict__ eg, const __hip_bfloat16* __restrict__ h2b,
        const __hip_bfloat16* __restrict__ w1t, const float* __restrict__ bc1,
        const __hip_bfloat16* __restrict__ w2t, const float* __restrict__ bc2,
        float* __restrict__ out) {
    __shared__ char s_hid[4][16 * 256];  // per-wave [16 rows][128 bf16], swizzled; 16 KB
    int t = threadIdx.x;
    int wid = t >> 6, lane = t & 63;
    int m  = lane & 15;        // edge-within-wave (A row / B col)
    int g4 = lane >> 4;        // k-group
    int ebase = blockIdx.x * 64 + wid * 16;
    int e = ebase + m;
    int s = eg[e], d = eg[E_GT + e];

    // A-frags: edge_feat[m][k], k = kk*32 + g4*8 + j  (k<128: h2[s], else h2[d])
    short8 a[8];
#pragma unroll
    for (int kk = 0; kk < 8; ++kk) {
        int node = (kk < 4) ? s : d;
        a[kk] = *(const short8*)(h2b + node * 128 + (kk & 3) * 32 + g4 * 8);
    }

    // GEMM1: 8 n-tiles of 16 outputs
    f32x4 acc[8];
#pragma unroll
    for (int nt = 0; nt < 8; ++nt) acc[nt] = (f32x4){0.f, 0.f, 0.f, 0.f};
#pragma unroll
    for (int nt = 0; nt < 8; ++nt) {
        const __hip_bfloat16* bp = w1t + (nt * 16 + m) * 256 + g4 * 8;
#pragma unroll
        for (int kk = 0; kk < 8; ++kk) {
            short8 b = *(const short8*)(bp + kk * 32);
            acc[nt] = __builtin_amdgcn_mfma_f32_16x16x32_bf16(a[kk], b, acc[nt], 0, 0, 0);
        }
    }

    // bias + relu -> swizzled LDS (row = edge, col = hidden channel)
#pragma unroll
    for (int nt = 0; nt < 8; ++nt) {
        float b1v = bc1[nt * 16 + m];
#pragma unroll
        for (int r = 0; r < 4; ++r) {
            int row = g4 * 4 + r;
            float v = fmaxf(acc[nt][r] + b1v, 0.0f);
            int colb = (nt * 16 + m) * 2;
            *(__hip_bfloat16*)(&s_hid[wid][row * 256 + (colb ^ ((row & 7) << 4))]) =
                __float2bfloat16(v);
        }
    }
    __syncthreads();

    // A2-frags: hid[m][k], k = kk*32 + g4*8 + j
    short8 a2[4];
#pragma unroll
    for (int kk = 0; kk < 4; ++kk) {
        int colb = kk * 64 + g4 * 16;
        a2[kk] = *(const short8*)(&s_hid[wid][m * 256 + (colb ^ ((m & 7) << 4))]);
    }

    // GEMM2: 35 n-tiles (552 outputs, padded to 560)
    for (int nt = 0; nt < 35; ++nt) {
        f32x4 acc2 = (f32x4){0.f, 0.f, 0.f, 0.f};
        const __hip_bfloat16* bp = w2t + (nt * 16 + m) * 128 + g4 * 8;
#pragma unroll
        for (int kk = 0; kk < 4; ++kk) {
            short8 b = *(const short8*)(bp + kk * 32);
            acc2 = __builtin_amdgcn_mfma_f32_16x16x32_bf16(a2[kk], b, acc2, 0, 0, 0);
        }
        int o = nt * 16 + m;
        if (o < 552) {
            float b2v = bc2[o];
#pragma unroll
            for (int r = 0; r < 4; ++r) {
                int row = ebase + g4 * 4 + r;
                float z = acc2[r] + b2v;
                out[row * 552 + o] = 1.0f / (1.0f + __expf(-z));
            }
        }
    }
}

extern "C" void kernel_launch(void* const* d_in, const int* in_sizes, int n_in,
                              void* d_out, int out_size, void* d_ws, size_t ws_size,
                              hipStream_t stream) {
    const float* x    = (const float*)d_in[0];
    const int*   ei   = (const int*)d_in[1];
    const int*   eg   = (const int*)d_in[2];
    const int*   ef   = (const int*)d_in[3];
    const float* embT = (const float*)d_in[4];
    const float* embA = (const float*)d_in[5];
    const float* W1l  = (const float*)d_in[6];
    const float* W1r  = (const float*)d_in[7];
    const float* b1   = (const float*)d_in[8];
    const float* W2l  = (const float*)d_in[9];
    const float* W2r  = (const float*)d_in[10];
    const float* b2   = (const float*)d_in[11];
    const float* Wc1  = (const float*)d_in[12];
    const float* bc1  = (const float*)d_in[13];
    const float* Wc2  = (const float*)d_in[14];
    const float* bc2  = (const float*)d_in[15];
    float* out = (float*)d_out;

    float* h0   = (float*)d_ws;            // N*24
    float* deg  = h0   + N_NODES * 24;     // N
    float* agg1 = deg  + N_NODES;          // N*24
    float* agg2 = agg1 + N_NODES * 24;     // N*256
    float* h1   = agg2 + N_NODES * 256;    // N*256
    __hip_bfloat16* h2b = (__hip_bfloat16*)(h1 + N_NODES * 256);  // N*128 bf16
    __hip_bfloat16* w1t = h2b + N_NODES * 128;                    // 128*256 bf16
    __hip_bfloat16* w2t = w1t + 128 * 256;                        // 560*128 bf16

    // zero deg + agg1 + agg2 in one memset (contiguous)
    hipMemsetAsync(deg, 0, (size_t)N_NODES * (1 + 24 + 256) * sizeof(float), stream);

    k_prep_w<<<(560 * 128 + 255) / 256, 256, 0, stream>>>(Wc1, Wc2, w1t, w2t);
    k_init_h0<<<(N_NODES * 24 + 255) / 256, 256, 0, stream>>>(x, h0);
    k_edge_embed<<<(E_EDGES + 255) / 256, 256, 0, stream>>>(ei, ef, embT, embA, h0, deg);
    k_agg24<<<(E_EDGES * 24 + 255) / 256, 256, 0, stream>>>(ei, h0, agg1);
    k_sage1<<<N_NODES / 8, 256, 0, stream>>>(agg1, h0, deg, W1l, W1r, b1, h1);
    k_agg256<<<E_EDGES, 256, 0, stream>>>(ei, h1, agg2);
    k_sage2<<<N_NODES / 8, 128, 0, stream>>>(agg2, h1, deg, W2l, W2r, b2, h2b);
    k_classifier_mfma<<<E_GT / 64, 256, 0, stream>>>(eg, h2b, w1t, bc1, w2t, bc2, out);
}